// Round 3
// baseline (196.602 us; speedup 1.0000x reference)
//
#include <hip/hip_runtime.h>

typedef __bf16 bf16;
typedef bf16 bf16x8 __attribute__((ext_vector_type(8)));
typedef bf16 bf16x4 __attribute__((ext_vector_type(4)));
typedef float f32x4 __attribute__((ext_vector_type(4)));
typedef unsigned int u32;
typedef u32 u32x4 __attribute__((ext_vector_type(4)));

#define SEQ 256
#define DH  32
#define TRI_PAD 288     // bf16 row stride 576B = 9 sectors -> all 16 L2 channels
#define KROW 40         // Kc/Tc row stride (bf16): 80B, 16B-aligned, 20-bank rotate
#define VROW 264        // Vt row stride (bf16): 528B, 16B-aligned

// ---------- pre-pass: tri fp32 -> bf16, rows padded to TRI_PAD ----------
__global__ void tri_cvt_kernel(const float* __restrict__ tri, bf16* __restrict__ tri16) {
    const int row = blockIdx.x;            // h*256 + s  (1024 rows)
    const int tid = threadIdx.x;           // 256
    tri16[(size_t)row * TRI_PAD + tid] = (bf16)tri[(size_t)row * SEQ + tid];
}

// ---------- main: one block per (n,h), 512 threads = 8 waves x 32 queries ----------
__global__ __launch_bounds__(512, 4) void attn_mfma2_kernel(
    const float* __restrict__ q,
    const float* __restrict__ k,
    const float* __restrict__ v,
    const float* __restrict__ mask_bias,   // [N][SEQ]
    const bf16*  __restrict__ tri16,       // [H][SEQ][TRI_PAD]
    float* __restrict__ out)
{
    // LDS arena: Kc [256][40]b (20480) | Vt [32][264]b (16896) | Tc [256][40]b (20480)
    // Epilogue overlays bytes [0, 36864) as Ob fp32 [256][36].
    __shared__ __align__(16) char arena[57856];
    bf16*  Kc = (bf16*)arena;
    bf16*  Vt = (bf16*)(arena + 20480);
    bf16*  Tc = (bf16*)(arena + 37376);
    float* Ob = (float*)arena;

    const int tid  = threadIdx.x;
    const int wave = tid >> 6;
    const int lane = tid & 63;
    const int l15  = lane & 15;
    const int quad = lane >> 4;

    const int inst = blockIdx.x;           // n*4 + h ; identity -> each XCD sees one h
    const int n    = inst >> 2;
    const int h    = inst & 3;

    const float* qb = q + (size_t)inst * SEQ * DH;
    const float* kb = k + (size_t)inst * SEQ * DH;
    const float* vb = v + (size_t)inst * SEQ * DH;
    const float* mb = mask_bias + (size_t)n * SEQ;
    const bf16*  tb = tri16 + (size_t)h * SEQ * TRI_PAD;
    float* ob = out + (size_t)inst * SEQ * DH;

    const float K1    = 0.17677669529663687f * 1.44269504088896f; // sm_scale*log2e
    const float LOG2E = 1.44269504088896f;
    const f32x4 zero4 = {0.f, 0.f, 0.f, 0.f};

    // ---- stage Q->Tc, K->Kc, V^T->Vt (bf16), fully coalesced global reads ----
    #pragma unroll
    for (int i = 0; i < 4; ++i) {
        int p  = i * 512 + tid;            // float4 piece: row = p>>3, d4 = (p&7)*4
        int s  = p >> 3;
        int d4 = (p & 7) * 4;
        float4 fq = ((const float4*)qb)[p];
        float4 fk = ((const float4*)kb)[p];
        float4 fv = ((const float4*)vb)[p];
        bf16x4 q4; q4[0]=(bf16)fq.x; q4[1]=(bf16)fq.y; q4[2]=(bf16)fq.z; q4[3]=(bf16)fq.w;
        *(bf16x4*)&Tc[s * KROW + d4] = q4;
        bf16x4 k4; k4[0]=(bf16)fk.x; k4[1]=(bf16)fk.y; k4[2]=(bf16)fk.z; k4[3]=(bf16)fk.w;
        *(bf16x4*)&Kc[s * KROW + d4] = k4;
        Vt[(d4 + 0) * VROW + s] = (bf16)fv.x;
        Vt[(d4 + 1) * VROW + s] = (bf16)fv.y;
        Vt[(d4 + 2) * VROW + s] = (bf16)fv.z;
        Vt[(d4 + 3) * VROW + s] = (bf16)fv.w;
    }

    // tri chunk-0 prefetch (independent of staging) — 1024 16B pieces, 2/thread
    const int p0 = tid, p1 = tid + 512;
    u32x4 R0 = *(const u32x4*)(tb + (size_t)(p0 >> 2) * TRI_PAD + (p0 & 3) * 8);
    u32x4 R1 = *(const u32x4*)(tb + (size_t)(p1 >> 2) * TRI_PAD + (p1 & 3) * 8);

    __syncthreads();

    // Q fragments for this wave's 32 queries (2 s-tiles of 16)
    bf16x8 qfrag[2];
    qfrag[0] = *(const bf16x8*)&Tc[(wave * 32 + l15) * KROW + quad * 8];
    qfrag[1] = *(const bf16x8*)&Tc[(wave * 32 + 16 + l15) * KROW + quad * 8];

    f32x4 oacc[2][2];
    #pragma unroll
    for (int st = 0; st < 2; ++st)
        #pragma unroll
        for (int dt = 0; dt < 2; ++dt)
            oacc[st][dt] = zero4;
    float lpart[2] = {0.f, 0.f};

    // ---- main loop: 8 chunks of 32 keys ----
    for (int c = 0; c < 8; ++c) {
        __syncthreads();   // prior chunk's P reads (and c=0: qfrag reads) done
        *(u32x4*)&Tc[(p0 >> 2) * KROW + (p0 & 3) * 8] = R0;
        *(u32x4*)&Tc[(p1 >> 2) * KROW + (p1 & 3) * 8] = R1;
        if (c < 7) {
            R0 = *(const u32x4*)(tb + (size_t)(p0 >> 2) * TRI_PAD + (c + 1) * 32 + (p0 & 3) * 8);
            R1 = *(const u32x4*)(tb + (size_t)(p1 >> 2) * TRI_PAD + (c + 1) * 32 + (p1 & 3) * 8);
        }
        __syncthreads();

        #pragma unroll
        for (int half = 0; half < 2; ++half) {
            const int t0h = c * 32 + half * 16;
            bf16x8 kfrag = *(const bf16x8*)&Kc[(t0h + l15) * KROW + quad * 8];
            float4 mk = *(const float4*)(mb + t0h + quad * 4);
            float mkl0 = mk.x * LOG2E, mkl1 = mk.y * LOG2E;
            float mkl2 = mk.z * LOG2E, mkl3 = mk.w * LOG2E;

            #pragma unroll
            for (int st = 0; st < 2; ++st) {
                const int srow = wave * 32 + st * 16 + l15;
                bf16x4 t4 = *(const bf16x4*)&Tc[srow * KROW + half * 16 + quad * 4];
                f32x4 cf = __builtin_amdgcn_mfma_f32_16x16x32_bf16(kfrag, qfrag[st], zero4, 0, 0, 0);
                float s0 = fmaf(cf[0], K1, fmaf((float)t4[0], LOG2E, mkl0));
                float s1 = fmaf(cf[1], K1, fmaf((float)t4[1], LOG2E, mkl1));
                float s2 = fmaf(cf[2], K1, fmaf((float)t4[2], LOG2E, mkl2));
                float s3 = fmaf(cf[3], K1, fmaf((float)t4[3], LOG2E, mkl3));
                float e0 = __builtin_amdgcn_exp2f(s0);
                float e1 = __builtin_amdgcn_exp2f(s1);
                float e2 = __builtin_amdgcn_exp2f(s2);
                float e3 = __builtin_amdgcn_exp2f(s3);
                lpart[st] += (e0 + e1) + (e2 + e3);
                bf16x4 pk; pk[0]=(bf16)e0; pk[1]=(bf16)e1; pk[2]=(bf16)e2; pk[3]=(bf16)e3;
                *(bf16x4*)&Tc[srow * KROW + half * 16 + quad * 4] = pk;  // overwrite consumed tri
            }
        }

        // ---- PV over this 32-key chunk (P rows are wave-private: no barrier) ----
        bf16x8 vf0 = *(const bf16x8*)&Vt[(l15) * VROW + c * 32 + quad * 8];
        bf16x8 vf1 = *(const bf16x8*)&Vt[(16 + l15) * VROW + c * 32 + quad * 8];
        #pragma unroll
        for (int st = 0; st < 2; ++st) {
            bf16x8 pf = *(const bf16x8*)&Tc[(wave * 32 + st * 16 + l15) * KROW + quad * 8];
            oacc[st][0] = __builtin_amdgcn_mfma_f32_16x16x32_bf16(pf, vf0, oacc[st][0], 0, 0, 0);
            oacc[st][1] = __builtin_amdgcn_mfma_f32_16x16x32_bf16(pf, vf1, oacc[st][1], 0, 0, 0);
        }
    }

    // ---- softmax denominators ----
    float linv[2];
    #pragma unroll
    for (int st = 0; st < 2; ++st) {
        float x = lpart[st];
        x += __shfl_xor(x, 16);
        x += __shfl_xor(x, 32);
        linv[st] = 1.0f / x;               // valid for row l15 of tile st (all quads)
    }

    __syncthreads();   // everything in arena dead -> overlay Ob

    #pragma unroll
    for (int st = 0; st < 2; ++st) {
        #pragma unroll
        for (int r = 0; r < 4; ++r) {
            float invr = __shfl(linv[st], quad * 4 + r);
            int s = wave * 32 + st * 16 + quad * 4 + r;
            Ob[s * 36 + l15]      = oacc[st][0][r] * invr;
            Ob[s * 36 + 16 + l15] = oacc[st][1][r] * invr;
        }
    }
    __syncthreads();

    // coalesced fp32 output store
    #pragma unroll
    for (int i = 0; i < 4; ++i) {
        int p  = i * 512 + tid;
        int s  = p >> 3;
        int d4 = (p & 7) * 4;
        f32x4 o = *(const f32x4*)&Ob[s * 36 + d4];
        float4 w; w.x = o[0]; w.y = o[1]; w.z = o[2]; w.w = o[3];
        ((float4*)ob)[p] = w;
    }
}

extern "C" void kernel_launch(void* const* d_in, const int* in_sizes, int n_in,
                              void* d_out, int out_size, void* d_ws, size_t ws_size,
                              hipStream_t stream) {
    const float* q    = (const float*)d_in[0];
    const float* k    = (const float*)d_in[1];
    const float* v    = (const float*)d_in[2];
    const float* mask = (const float*)d_in[3];
    const float* tri  = (const float*)d_in[4];
    float* out = (float*)d_out;

    bf16* tri16 = (bf16*)d_ws;   // 4*256*288*2 = 589824 B

    tri_cvt_kernel<<<dim3(4 * SEQ), dim3(SEQ), 0, stream>>>(tri, tri16);
    attn_mfma2_kernel<<<dim3(SEQ * 4), dim3(512), 0, stream>>>(q, k, v, mask, tri16, out);
}

// Round 4
// 186.799 us; speedup vs baseline: 1.0525x; 1.0525x over previous
//
#include <hip/hip_runtime.h>

typedef __bf16 bf16;
typedef bf16 bf16x8 __attribute__((ext_vector_type(8)));
typedef bf16 bf16x4 __attribute__((ext_vector_type(4)));
typedef float f32x4 __attribute__((ext_vector_type(4)));

#define SEQ 256
#define DH  32
#define VROW 264     // Vt row stride (bf16): 528B, 16B multiple
#define PROW 40      // Pb row stride (bf16): 80B, 16B multiple

// One block = (n, h, query-half): 256 threads = 4 waves, wave owns 32 queries.
// Inner loop is barrier-free (P buffer is wave-private). tri/K for chunk c+1
// are register-prefetched while PV of chunk c runs.
__global__ __launch_bounds__(256, 5) void attn_mfma4_kernel(
    const float* __restrict__ q,
    const float* __restrict__ k,
    const float* __restrict__ v,
    const float* __restrict__ mask_bias,   // [N][SEQ]
    const float* __restrict__ tri_bias,    // [H][SEQ][SEQ]
    float* __restrict__ out)
{
    __shared__ bf16  Vt[DH][VROW];         // 16896 B
    __shared__ bf16  Pb[4][32][PROW];      // 10240 B (wave-private rows)
    __shared__ float Mc[SEQ];              //  1024 B   -> total 28160 B, 5 blocks/CU

    const int tid  = threadIdx.x;
    const int wave = tid >> 6;
    const int lane = tid & 63;
    const int l15  = lane & 15;
    const int quad = lane >> 4;

    // XCD-aware decode: xcd = b&7 fixed per XCD slice; h = xcd&3 -> each XCD's
    // 256KB tri slice stays L2-resident.
    const int b     = blockIdx.x;          // 0..2047
    const int xcd   = b & 7;
    const int j     = b >> 3;              // 0..255
    const int h     = xcd & 3;
    const int n     = (j >> 1) + ((xcd >> 2) << 7);
    const int qhalf = j & 1;
    const int inst  = n * 4 + h;

    const float* qb = q + (size_t)inst * SEQ * DH;
    const float* kb = k + (size_t)inst * SEQ * DH;
    const float* vb = v + (size_t)inst * SEQ * DH;
    const float* mb = mask_bias + (size_t)n * SEQ;
    const float* tb = tri_bias + (size_t)h * SEQ * SEQ;
    float*       ob = out + (size_t)inst * SEQ * DH;

    const int s0 = qhalf * 128 + wave * 32;   // this wave's first query row

    const float K1    = 0.17677669529663687f * 1.44269504088896f; // sm_scale*log2e
    const float LOG2E = 1.44269504088896f;
    const f32x4 zero4 = {0.f, 0.f, 0.f, 0.f};

    // ---- stage V^T (bf16) + mask row into LDS; coalesced global reads ----
    #pragma unroll
    for (int i = 0; i < 8; ++i) {
        int idx = i * 256 + tid;           // float4 piece: t = idx>>3, d4 = (idx&7)*4
        int t = idx >> 3;
        int d = (idx & 7) * 4;
        float4 fv = ((const float4*)vb)[idx];
        Vt[d + 0][t] = (bf16)fv.x;
        Vt[d + 1][t] = (bf16)fv.y;
        Vt[d + 2][t] = (bf16)fv.z;
        Vt[d + 3][t] = (bf16)fv.w;
    }
    Mc[tid] = mb[tid];

    // ---- Q b-frags for this wave's 32 queries (2 s-tiles), straight from global ----
    bf16x8 qfrag[2];
    #pragma unroll
    for (int st = 0; st < 2; ++st) {
        const float* p = qb + (size_t)(s0 + st * 16 + l15) * DH + quad * 8;
        float4 a = ((const float4*)p)[0];
        float4 c4 = ((const float4*)p)[1];
        bf16x8 f;
        f[0]=(bf16)a.x;  f[1]=(bf16)a.y;  f[2]=(bf16)a.z;  f[3]=(bf16)a.w;
        f[4]=(bf16)c4.x; f[5]=(bf16)c4.y; f[6]=(bf16)c4.z; f[7]=(bf16)c4.w;
        qfrag[st] = f;
    }

    // ---- preload chunk 0 tri + K into registers ----
    const float* trp0 = tb + (size_t)(s0 + l15) * SEQ;        // st=0 row for this lane
    const float* trp1 = tb + (size_t)(s0 + 16 + l15) * SEQ;   // st=1 row
    float4 t00 = *(const float4*)(trp0 + quad * 4);           // half0, st0
    float4 t01 = *(const float4*)(trp1 + quad * 4);           // half0, st1
    float4 t10 = *(const float4*)(trp0 + 16 + quad * 4);      // half1, st0
    float4 t11 = *(const float4*)(trp1 + 16 + quad * 4);      // half1, st1
    float4 k0a = *(const float4*)(kb + (l15) * DH + quad * 8);
    float4 k0b = *(const float4*)(kb + (l15) * DH + quad * 8 + 4);
    float4 k1a = *(const float4*)(kb + (16 + l15) * DH + quad * 8);
    float4 k1b = *(const float4*)(kb + (16 + l15) * DH + quad * 8 + 4);

    __syncthreads();   // Vt + Mc ready

    f32x4 oacc[2][2];
    #pragma unroll
    for (int st = 0; st < 2; ++st)
        #pragma unroll
        for (int dt = 0; dt < 2; ++dt)
            oacc[st][dt] = zero4;
    float lpart[2] = {0.f, 0.f};

    // ---- main loop: 8 chunks of 32 keys, barrier-free ----
    for (int c = 0; c < 8; ++c) {
        #pragma unroll
        for (int half = 0; half < 2; ++half) {
            float4 ka = half ? k1a : k0a;
            float4 kc = half ? k1b : k0b;
            bf16x8 kfrag;
            kfrag[0]=(bf16)ka.x; kfrag[1]=(bf16)ka.y; kfrag[2]=(bf16)ka.z; kfrag[3]=(bf16)ka.w;
            kfrag[4]=(bf16)kc.x; kfrag[5]=(bf16)kc.y; kfrag[6]=(bf16)kc.z; kfrag[7]=(bf16)kc.w;

            float4 mk = *(const float4*)&Mc[c * 32 + half * 16 + quad * 4];
            float mkl0 = mk.x * LOG2E, mkl1 = mk.y * LOG2E;
            float mkl2 = mk.z * LOG2E, mkl3 = mk.w * LOG2E;

            #pragma unroll
            for (int st = 0; st < 2; ++st) {
                float4 tr = half ? (st ? t11 : t10) : (st ? t01 : t00);
                f32x4 cf = __builtin_amdgcn_mfma_f32_16x16x32_bf16(kfrag, qfrag[st], zero4, 0, 0, 0);
                float e0 = __builtin_amdgcn_exp2f(fmaf(cf[0], K1, fmaf(tr.x, LOG2E, mkl0)));
                float e1 = __builtin_amdgcn_exp2f(fmaf(cf[1], K1, fmaf(tr.y, LOG2E, mkl1)));
                float e2 = __builtin_amdgcn_exp2f(fmaf(cf[2], K1, fmaf(tr.z, LOG2E, mkl2)));
                float e3 = __builtin_amdgcn_exp2f(fmaf(cf[3], K1, fmaf(tr.w, LOG2E, mkl3)));
                lpart[st] += (e0 + e1) + (e2 + e3);
                bf16x4 pk; pk[0]=(bf16)e0; pk[1]=(bf16)e1; pk[2]=(bf16)e2; pk[3]=(bf16)e3;
                *(bf16x4*)&Pb[wave][st * 16 + l15][half * 16 + quad * 4] = pk;
            }
        }

        // ---- register-prefetch chunk c+1's tri + K (consumed next iteration;
        //      issued here so PV below + next chunk top hide the latency) ----
        {
            const int cn = (c + 1) & 7;    // c==7 reloads chunk 0 (discarded) — branchless
            t00 = *(const float4*)(trp0 + cn * 32 + quad * 4);
            t01 = *(const float4*)(trp1 + cn * 32 + quad * 4);
            t10 = *(const float4*)(trp0 + cn * 32 + 16 + quad * 4);
            t11 = *(const float4*)(trp1 + cn * 32 + 16 + quad * 4);
            k0a = *(const float4*)(kb + (cn * 32 + l15) * DH + quad * 8);
            k0b = *(const float4*)(kb + (cn * 32 + l15) * DH + quad * 8 + 4);
            k1a = *(const float4*)(kb + (cn * 32 + 16 + l15) * DH + quad * 8);
            k1b = *(const float4*)(kb + (cn * 32 + 16 + l15) * DH + quad * 8 + 4);
        }

        // ---- PV over this 32-key chunk (wave-private P rows: no barrier) ----
        bf16x8 vf0 = *(const bf16x8*)&Vt[l15][c * 32 + quad * 8];
        bf16x8 vf1 = *(const bf16x8*)&Vt[16 + l15][c * 32 + quad * 8];
        #pragma unroll
        for (int st = 0; st < 2; ++st) {
            bf16x8 pf = *(const bf16x8*)&Pb[wave][st * 16 + l15][quad * 8];
            oacc[st][0] = __builtin_amdgcn_mfma_f32_16x16x32_bf16(pf, vf0, oacc[st][0], 0, 0, 0);
            oacc[st][1] = __builtin_amdgcn_mfma_f32_16x16x32_bf16(pf, vf1, oacc[st][1], 0, 0, 0);
        }
    }

    // ---- softmax denominators: reduce over quads in-register ----
    float linv[2];
    #pragma unroll
    for (int st = 0; st < 2; ++st) {
        float x = lpart[st];
        x += __shfl_xor(x, 16);
        x += __shfl_xor(x, 32);
        linv[st] = 1.0f / x;               // valid for local row l15 (all quads)
    }

    // ---- normalize + store (direct global stores, 64B segments per quad) ----
    #pragma unroll
    for (int st = 0; st < 2; ++st) {
        #pragma unroll
        for (int r = 0; r < 4; ++r) {
            float invr = __shfl(linv[st], quad * 4 + r);
            int s = s0 + st * 16 + quad * 4 + r;
            float* orow = ob + (size_t)s * DH;
            orow[l15]      = oacc[st][0][r] * invr;
            orow[16 + l15] = oacc[st][1][r] * invr;
        }
    }
}

extern "C" void kernel_launch(void* const* d_in, const int* in_sizes, int n_in,
                              void* d_out, int out_size, void* d_ws, size_t ws_size,
                              hipStream_t stream) {
    const float* q    = (const float*)d_in[0];
    const float* k    = (const float*)d_in[1];
    const float* v    = (const float*)d_in[2];
    const float* mask = (const float*)d_in[3];
    const float* tri  = (const float*)d_in[4];
    float* out = (float*)d_out;

    attn_mfma4_kernel<<<dim3(2048), dim3(256), 0, stream>>>(q, k, v, mask, tri, out);
}